// Round 4
// baseline (41.279 us; speedup 1.0000x reference)
//
#include <hip/hip_runtime.h>
#include <math.h>

// Problem constants (match reference)
#define BB 8
#define NN 4096
#define LATENT 256

#define THREADS 256
#define Q 4                          // queries per thread
#define QB (Q * THREADS)             // 1024 queries per block
#define QTILES (NN / QB)             // 4
#define BLOCKS_X (2 * BB * QTILES)   // 64  (dir x batch x qtile)
#define CSPLIT 32                    // candidate tiles
#define TT (NN / CSPLIT)             // 128 candidates per tile
#define NSLOTS (2 * BB * NN)         // 65536 query slots

// Order-preserving float<->uint encoding (monotone: f1<f2 <=> enc(f1)<enc(f2))
__device__ __forceinline__ unsigned enc(float f) {
    unsigned b = __float_as_uint(f);
    return (b & 0x80000000u) ? ~b : (b | 0x80000000u);
}
__device__ __forceinline__ float dec(unsigned k) {
    unsigned b = (k & 0x80000000u) ? (k ^ 0x80000000u) : ~k;
    return __uint_as_float(b);
}

// ---------------------------------------------------------------------------
// Stage 1: block (bx, c) = (dir,b,qtile) x candidate-tile c.
// Stages TT candidates into LDS as {-2y0,-2y1,-2y2,|y|^2}; each thread scans
// the tile for its 4 query points (software-pipelined 2-candidate steps,
// min3 fusion), then atomicMin's the encoded tile-min into minkeys[slot].
// Min is order-independent -> deterministic.
// ---------------------------------------------------------------------------
__global__ __launch_bounds__(THREADS, 6)
void chamfer_stage1(const float* __restrict__ recon,
                    const float* __restrict__ x,
                    unsigned* __restrict__ minkeys,
                    unsigned* __restrict__ counter)
{
    __shared__ float4 ly[TT];        // 2 KB

    const int bx  = blockIdx.x;      // 0..63
    const int c   = blockIdx.y;      // 0..31
    const int dir = bx >> 5;
    const int rem = bx & 31;
    const int b   = rem >> 2;
    const int qt  = rem & 3;
    const int tid = threadIdx.x;

    // Reset the stage-2 completion counter once per launch (kernel-boundary
    // ordering makes this visible to stage 2).
    if (bx == 0 && c == 0 && tid == 0) *counter = 0u;

    const float* cloud = (dir ? recon : x) + (size_t)b * 3 * NN;
    const float* query = (dir ? x : recon) + (size_t)b * 3 * NN;

    // Stage candidate tile (pre-scaled) into LDS
    for (int i = tid; i < TT; i += THREADS) {
        int m = c * TT + i;
        float y0 = cloud[m];
        float y1 = cloud[NN + m];
        float y2 = cloud[2 * NN + m];
        ly[i] = make_float4(-2.0f * y0, -2.0f * y1, -2.0f * y2,
                            y0 * y0 + y1 * y1 + y2 * y2);
    }
    __syncthreads();

    const int q0 = qt * QB + tid;
    float px[Q], py[Q], pz[Q], mn[Q];
#pragma unroll
    for (int k = 0; k < Q; ++k) {
        int q = q0 + k * THREADS;
        px[k] = query[q];
        py[k] = query[NN + q];
        pz[k] = query[2 * NN + q];
        mn[k] = 3.4e38f;
    }

    // Software-pipelined scan: prefetch next 2 candidates before computing.
    float4 va = ly[0], vb = ly[1];
#pragma unroll 4
    for (int m = 0; m < TT - 2; m += 2) {
        float4 na = ly[m + 2];
        float4 nb = ly[m + 3];
#pragma unroll
        for (int k = 0; k < Q; ++k) {
            float t0 = fmaf(px[k], va.x, fmaf(py[k], va.y, fmaf(pz[k], va.z, va.w)));
            float t1 = fmaf(px[k], vb.x, fmaf(py[k], vb.y, fmaf(pz[k], vb.z, vb.w)));
            mn[k] = fminf(fminf(mn[k], t0), t1);   // -> v_min3_f32
        }
        va = na; vb = nb;
    }
#pragma unroll
    for (int k = 0; k < Q; ++k) {
        float t0 = fmaf(px[k], va.x, fmaf(py[k], va.y, fmaf(pz[k], va.z, va.w)));
        float t1 = fmaf(px[k], vb.x, fmaf(py[k], vb.y, fmaf(pz[k], vb.z, vb.w)));
        mn[k] = fminf(fminf(mn[k], t0), t1);
        float sx  = fmaf(px[k], px[k], fmaf(py[k], py[k], pz[k] * pz[k]));
        float val = sx + mn[k];
        int slot  = dir * (BB * NN) + b * NN + q0 + k * THREADS;
        atomicMin(&minkeys[slot], enc(val));
    }
}

// ---------------------------------------------------------------------------
// Stage 2 + finalize (last-block pattern): decode per-query mins, block-sum;
// the last block to finish sums the 256 block totals, adds KL, writes out.
// ---------------------------------------------------------------------------
__global__ __launch_bounds__(THREADS)
void chamfer_stage2(const unsigned* __restrict__ minkeys,
                    const float* __restrict__ mu,
                    const float* __restrict__ logvar,
                    float* __restrict__ sums,
                    unsigned* __restrict__ counter,
                    float* __restrict__ out)
{
    __shared__ float red[4];
    __shared__ float redA[4];
    __shared__ float redB[4];
    __shared__ int amLast;

    const int tid = threadIdx.x;
    const int bid = blockIdx.x;

    float v = dec(minkeys[bid * THREADS + tid]);
    for (int off = 32; off > 0; off >>= 1)
        v += __shfl_down(v, off);
    if ((tid & 63) == 0) red[tid >> 6] = v;
    __syncthreads();

    if (tid == 0) {
        float tot = red[0] + red[1] + red[2] + red[3];
        __hip_atomic_store(&sums[bid], tot, __ATOMIC_RELEASE, __HIP_MEMORY_SCOPE_AGENT);
        unsigned old = __hip_atomic_fetch_add(counter, 1u, __ATOMIC_ACQ_REL, __HIP_MEMORY_SCOPE_AGENT);
        amLast = (old == 255u);
    }
    __syncthreads();
    if (!amLast) return;

    // Final block: sum 256 block totals + KL over 8x256, write 3 outputs.
    float s = __hip_atomic_load(&sums[tid], __ATOMIC_ACQUIRE, __HIP_MEMORY_SCOPE_AGENT);

    float kl = 0.0f;
    for (int i = tid; i < BB * LATENT; i += THREADS) {
        float m  = mu[i];
        float lv = logvar[i];
        kl += 1.0f + lv - m * m - expf(lv);
    }

    for (int off = 32; off > 0; off >>= 1) {
        s  += __shfl_down(s, off);
        kl += __shfl_down(kl, off);
    }
    if ((tid & 63) == 0) { redA[tid >> 6] = s; redB[tid >> 6] = kl; }
    __syncthreads();
    if (tid == 0) {
        float recon = (redA[0] + redA[1] + redA[2] + redA[3]) / (float)(BB * NN);
        float kld   = -0.5f * (redB[0] + redB[1] + redB[2] + redB[3]) / (float)BB;
        out[0] = recon + kld;   // BETA = 1
        out[1] = recon;
        out[2] = kld;
    }
}

extern "C" void kernel_launch(void* const* d_in, const int* in_sizes, int n_in,
                              void* d_out, int out_size, void* d_ws, size_t ws_size,
                              hipStream_t stream)
{
    const float* recon  = (const float*)d_in[0];
    const float* x      = (const float*)d_in[1];
    const float* mu     = (const float*)d_in[2];
    const float* logvar = (const float*)d_in[3];
    float* out = (float*)d_out;

    unsigned* minkeys = (unsigned*)d_ws;             // 65536 uints (256 KB)
    float*    sums    = (float*)(minkeys + NSLOTS);  // 256 floats
    unsigned* counter = (unsigned*)(sums + 256);     // 1 uint

    // Init min-keys to 0xFFFFFFFF (= +inf under enc ordering); capturable.
    hipMemsetAsync(minkeys, 0xFF, (size_t)NSLOTS * sizeof(unsigned), stream);

    dim3 g1(BLOCKS_X, CSPLIT);
    chamfer_stage1<<<g1, THREADS, 0, stream>>>(recon, x, minkeys, counter);
    chamfer_stage2<<<NSLOTS / THREADS, THREADS, 0, stream>>>(minkeys, mu, logvar,
                                                             sums, counter, out);
}